// Round 3
// baseline (41317.422 us; speedup 1.0000x reference)
//
#include <hip/hip_runtime.h>

#define EPSV 1e-5f

#define ATOMIC_LD(p)    __hip_atomic_load((p), __ATOMIC_RELAXED, __HIP_MEMORY_SCOPE_AGENT)
#define ATOMIC_ST(p, v) __hip_atomic_store((p), (v), __ATOMIC_RELAXED, __HIP_MEMORY_SCOPE_AGENT)

// ---------------- workspace layout (float offsets) ----------------
static constexpr long OFF_HG    = 0;                      // 8*512
static constexpr long OFF_RHG   = 4096;                   // 8*512
static constexpr long OFF_FLA   = 8192;                   // 8 batches * 64 uints (flagsA)
static constexpr long OFF_FLB   = 8704;                   // 8 batches * 64 uints (flagsB)
static constexpr long OFF_MEAN  = 9216;                   // 512
static constexpr long OFF_SCALE = 9728;                   // 512
static constexpr long OFF_OFFS  = 10240;                  // 512
static constexpr long OFF_U0    = 16384;                  // 8*38*512
static constexpr long OFF_U0N   = OFF_U0    + 155648;
static constexpr long OFF_R1    = OFF_U0N   + 155648;     // 8*36*512
static constexpr long OFF_U1    = OFF_R1    + 147456;
static constexpr long OFF_R2    = OFF_U1    + 147456;     // 8*32*512
static constexpr long OFF_U2    = OFF_R2    + 131072;
static constexpr long OFF_Y1    = OFF_U2    + 131072;     // 8*64*512
static constexpr long OFF_V1    = OFF_Y1    + 262144;
static constexpr long OFF_Y2    = OFF_V1    + 262144;     // 8*128*512
static constexpr long OFF_V2    = OFF_Y2    + 524288;
static constexpr long OFF_Y3    = OFF_V2    + 524288;     // 8*512*512
static constexpr long OFF_COND0 = OFF_Y3    + 2097152;
static constexpr long OFF_EWI   = OFF_COND0 + 2097152;    // 256*1536
static constexpr long OFF_CGX   = OFF_EWI   + 393216;     // 4096*1536
static constexpr long OFF_HSEQ  = OFF_CGX   + 6291456;    // 8*8192*512
// total ~46.9M floats (~180 MB)

__global__ void init_kernel(float* hg, float* rhg, unsigned* fA, unsigned* fB) {
    int t = blockIdx.x * 256 + threadIdx.x;
    if (t < 4096) { ATOMIC_ST(&hg[t], 0.f); ATOMIC_ST(&rhg[t], 0.f); }
    if (t < 512) {
        __hip_atomic_store(&fA[t], 0u, __ATOMIC_RELAXED, __HIP_MEMORY_SCOPE_AGENT);
        __hip_atomic_store(&fB[t], 0u, __ATOMIC_RELAXED, __HIP_MEMORY_SCOPE_AGENT);
    }
}

// generic dilated valid conv1d, Cout = blockDim.x
__global__ void conv1d_kernel(const float* __restrict__ in, const float* __restrict__ w,
                              const float* __restrict__ b, float* __restrict__ out,
                              int T_in, int T_out, int Cin, int K, int rate) {
    extern __shared__ float s_in[];
    int n = blockIdx.x / T_out, t = blockIdx.x % T_out;
    int Cout = blockDim.x;
    for (int idx = threadIdx.x; idx < K * Cin; idx += Cout) {
        int k = idx / Cin, i = idx - k * Cin;
        s_in[idx] = in[((long)(n * T_in + t + k * rate)) * Cin + i];
    }
    __syncthreads();
    int c = threadIdx.x;
    float acc = b[c];
    for (int j = 0; j < K * Cin; ++j)
        acc += s_in[j] * w[(long)j * Cout + c];
    out[((long)(n * T_out + t)) * Cout + c] = acc;
}

// conv_transpose, kernel=1, SAME: out[s] = (s%stride==0) ? in[s/stride]@w : 0, + b
__global__ void tconv1d_kernel(const float* __restrict__ in, const float* __restrict__ w,
                               const float* __restrict__ b, float* __restrict__ out,
                               int T_in, int stride, int Cin) {
    extern __shared__ float s_in[];
    int T_out = T_in * stride;
    int n = blockIdx.x / T_out, s = blockIdx.x % T_out;
    int Cout = blockDim.x;
    int c = threadIdx.x;
    if (s % stride) { out[((long)(n * T_out + s)) * Cout + c] = b[c]; return; }
    for (int i = threadIdx.x; i < Cin; i += Cout)
        s_in[i] = in[((long)(n * T_in + s / stride)) * Cin + i];
    __syncthreads();
    float acc = b[c];
    for (int i = 0; i < Cin; ++i) acc += s_in[i] * w[(long)i * Cout + c];
    out[((long)(n * T_out + s)) * Cout + c] = acc;
}

// per-channel batch stats -> mean, scale = s*rsqrt(var+eps), off
__global__ void bnstats_kernel(const float* __restrict__ x, const float* __restrict__ bns,
                               const float* __restrict__ bno, float* mean, float* scale,
                               float* offs, int count, int C) {
    int c = blockIdx.x, t = threadIdx.x;
    float s = 0.f, s2 = 0.f;
    for (int j = t; j < count; j += 64) { float v = x[(long)j * C + c]; s += v; s2 += v * v; }
    for (int off = 32; off; off >>= 1) { s += __shfl_down(s, off); s2 += __shfl_down(s2, off); }
    if (t == 0) {
        float m = s / count;
        float var = s2 / count - m * m;
        mean[c] = m;
        scale[c] = bns[c] * rsqrtf(var + EPSV);
        offs[c] = bno[c];
    }
}

__global__ void bnapply_kernel(const float* __restrict__ x, float* __restrict__ out,
                               const float* mean, const float* scale, const float* offs,
                               long total) {
    long i = (long)blockIdx.x * 256 + threadIdx.x;
    if (i >= total) return;
    int c = (int)(i & 511);
    float v = (x[i] - mean[c]) * scale[c] + offs[c];
    out[i] = fmaxf(v, 0.f);
}

// out[n,t] = base[n, t+shift] + relu(bn(r[n,t]))
__global__ void bnapply_add_kernel(const float* __restrict__ r, const float* __restrict__ base,
                                   float* __restrict__ out, const float* mean, const float* scale,
                                   const float* offs, int T_out, int T_base, int shift) {
    long i = (long)blockIdx.x * 256 + threadIdx.x;
    long total = (long)8 * T_out * 512;
    if (i >= total) return;
    int c = (int)(i & 511);
    long row = i >> 9;
    int n = (int)(row / T_out), t = (int)(row % T_out);
    float v = (r[i] - mean[c]) * scale[c] + offs[c];
    v = fmaxf(v, 0.f);
    out[i] = base[(((long)(n * T_base + t + shift)) << 9) + c] + v;
}

// out[rows x 1536] = A[rows x 512] @ W[512 x 1536]; grid = rows/16, block 256
__global__ void __launch_bounds__(256) rowgemm_kernel(const float* __restrict__ A,
                                                      const float* __restrict__ W,
                                                      float* __restrict__ out, int rows) {
    __shared__ float sA[16 * 512];
    long r0 = (long)blockIdx.x * 16;
    int t = threadIdx.x;
    for (int idx = t; idx < 16 * 512; idx += 256) sA[idx] = A[r0 * 512 + idx];
    __syncthreads();
    float acc[16][6];
#pragma unroll
    for (int r = 0; r < 16; ++r)
#pragma unroll
        for (int j = 0; j < 6; ++j) acc[r][j] = 0.f;
    for (int e = 0; e < 512; ++e) {
        float wv[6];
#pragma unroll
        for (int j = 0; j < 6; ++j) wv[j] = W[(long)e * 1536 + t + 256 * j];
#pragma unroll
        for (int r = 0; r < 16; ++r) {
            float a = sA[r * 512 + e];
#pragma unroll
            for (int j = 0; j < 6; ++j) acc[r][j] += a * wv[j];
        }
    }
    for (int r = 0; r < 16; ++r)
#pragma unroll
        for (int j = 0; j < 6; ++j) out[(r0 + r) * 1536 + t + 256 * j] = acc[r][j];
}

// ---------------- persistent GRU ----------------
// 256 wgs: batch n = blockIdx%8, role = blockIdx/8 (0..31), role owns 16 h-cols.
// Weights (f32) transposed+padded in LDS.
// Cross-WG sync: per-WG FLAG ARRAY (no contended RMW). Producer: data stores
// (relaxed agent atomics -> LLC), __syncthreads (drains vmcnt), t0 stores its
// epoch flag. Consumers: every wave polls the 32 flags with one coalesced
// 32-lane load + __all, then reads the data from LLC.
#define GRU_SMEM_FLOATS (3 * 16 * 520 + 512 + 512 + 64)

__device__ __forceinline__ void poll_flags(const unsigned* f, unsigned tgt) {
    int lane = threadIdx.x & 63;
    for (;;) {
        unsigned v = tgt;
        if (lane < 32) v = __hip_atomic_load(&f[lane], __ATOMIC_RELAXED, __HIP_MEMORY_SCOPE_AGENT);
        if (__all((int)(v >= tgt))) break;
        __builtin_amdgcn_s_sleep(1);
    }
    __builtin_amdgcn_sched_barrier(0);
}

__global__ void __launch_bounds__(256, 1) gru_kernel(
    const float* __restrict__ wh, const float* __restrict__ gb, const int* __restrict__ x,
    const float* __restrict__ ewi, const float* __restrict__ cgx,
    float* __restrict__ h_g, float* __restrict__ rh_g,
    unsigned* __restrict__ flagA, unsigned* __restrict__ flagB,
    float* __restrict__ hseq) {
    extern __shared__ float sm[];
    float* Wzt = sm;                    // [16][520]
    float* Wrt = Wzt + 16 * 520;
    float* Wat = Wrt + 16 * 520;
    float* h_l = Wat + 16 * 520;        // [512]
    float* rh_l = h_l + 512;            // [512]
    float* bz = rh_l + 512;             // [16]*3
    float* br = bz + 16;
    float* ba = br + 16;

    int wg = blockIdx.x;
    int n = wg & 7;
    int role = wg >> 3;
    int base = role * 16;
    int t = threadIdx.x;

    for (int idx = t; idx < 512 * 16; idx += 256) {
        int i = idx >> 4, c = idx & 15;
        Wzt[c * 520 + i] = wh[(long)i * 1536 + base + c];
        Wrt[c * 520 + i] = wh[(long)i * 1536 + 512 + base + c];
        Wat[c * 520 + i] = wh[(long)i * 1536 + 1024 + base + c];
    }
    if (t < 16) { bz[t] = gb[base + t]; br[t] = gb[512 + base + t]; ba[t] = gb[1024 + base + t]; }

    const float* cgxn = cgx + (long)n * 512 * 1536;
    unsigned* fA = flagA + n * 64;
    unsigned* fB = flagB + n * 64;
    float* hgn = h_g + n * 512;
    float* rhgn = rh_g + n * 512;

    int col = t >> 4, sub = t & 15;
    const float* Wz_c = Wzt + col * 520;
    const float* Wr_c = Wrt + col * 520;
    const float* Wa_c = Wat + col * 520;

    // initial h (zeros from init_kernel)
    h_l[t] = ATOMIC_LD(&hgn[t]);
    h_l[t + 256] = ATOMIC_LD(&hgn[t + 256]);
    __syncthreads();

    for (int l = 0; l < 8192; ++l) {
        unsigned ep = (unsigned)(l + 1);
        int xv = x[n * 8192 + l];
        const float* e_row = ewi + (long)xv * 1536;
        const float* c_row = cgxn + (long)(l >> 4) * 1536;

        // gate inputs (issued early; only the reducing lanes need them)
        float gz = 0.f, gr = 0.f, ga = 0.f;
        if (sub == 0) {
            gz = e_row[base + col] + c_row[base + col] + bz[col];
            gr = e_row[512 + base + col] + c_row[512 + base + col] + br[col];
            ga = e_row[1024 + base + col] + c_row[1024 + base + col] + ba[col];
        }

        // ---- phase A: r only (publish rh ASAP) ----
        float accr = 0.f;
#pragma unroll 8
        for (int k = 0; k < 32; ++k) {
            int i = sub + (k << 4);
            accr += h_l[i] * Wr_c[i];
        }
        accr += __shfl_down(accr, 8, 16);
        accr += __shfl_down(accr, 4, 16);
        accr += __shfl_down(accr, 2, 16);
        accr += __shfl_down(accr, 1, 16);
        if (sub == 0) {
            float rr = 1.f / (1.f + __expf(-(gr + accr)));
            ATOMIC_ST(&rhgn[base + col], rr * h_l[base + col]);
        }
        __syncthreads();              // drain rh stores (vmcnt(0) before s_barrier)
        if (t == 0) __hip_atomic_store(&fA[role], ep, __ATOMIC_RELAXED, __HIP_MEMORY_SCOPE_AGENT);

        // ---- overlap: z matvec while waiting ----
        float accz = 0.f;
#pragma unroll 8
        for (int k = 0; k < 32; ++k) {
            int i = sub + (k << 4);
            accz += h_l[i] * Wz_c[i];
        }
        accz += __shfl_down(accz, 8, 16);
        accz += __shfl_down(accz, 4, 16);
        accz += __shfl_down(accz, 2, 16);
        accz += __shfl_down(accz, 1, 16);
        float z = (sub == 0) ? 1.f / (1.f + __expf(-(gz + accz))) : 0.f;

        // ---- sync A: wait for full rh ----
        poll_flags(fA, ep);
        rh_l[t] = ATOMIC_LD(&rhgn[t]);
        rh_l[t + 256] = ATOMIC_LD(&rhgn[t + 256]);
        __syncthreads();

        // ---- phase B: a + h update ----
        float acca = 0.f;
#pragma unroll 8
        for (int k = 0; k < 32; ++k) {
            int i = sub + (k << 4);
            acca += rh_l[i] * Wa_c[i];
        }
        acca += __shfl_down(acca, 8, 16);
        acca += __shfl_down(acca, 4, 16);
        acca += __shfl_down(acca, 2, 16);
        acca += __shfl_down(acca, 1, 16);
        if (sub == 0) {
            float pre = ga + acca;
            float axv = fabsf(pre);
            float ex = __expf(-2.f * axv);
            float th = (1.f - ex) / (1.f + ex);
            float a = copysignf(th, pre);
            float hn = (1.f - z) * h_l[base + col] + z * a;
            ATOMIC_ST(&hgn[base + col], hn);
            hseq[(((long)n * 8192 + l) << 9) + base + col] = hn;
        }
        if (l == 8191) break;         // nobody consumes the last h via the barrier
        __syncthreads();              // drain h stores
        if (t == 0) __hip_atomic_store(&fB[role], ep, __ATOMIC_RELAXED, __HIP_MEMORY_SCOPE_AGENT);

        // ---- sync B: wait for full h(l+1) ----
        poll_flags(fB, ep);
        h_l[t] = ATOMIC_LD(&hgn[t]);
        h_l[t + 256] = ATOMIC_LD(&hgn[t + 256]);
        __syncthreads();
    }
}

// fused head: relu(h@o1+b1)@o2+b2 -> log_softmax; 16 rows per block
__global__ void __launch_bounds__(256) head_kernel(const float* __restrict__ hseq,
                                                   const float* __restrict__ o1w,
                                                   const float* __restrict__ o1b,
                                                   const float* __restrict__ o2w,
                                                   const float* __restrict__ o2b,
                                                   float* __restrict__ out) {
    __shared__ float hs[16 * 512];
    long row0 = (long)blockIdx.x * 16;
    int t = threadIdx.x;
    for (int idx = t; idx < 16 * 512; idx += 256) hs[idx] = hseq[row0 * 512 + idx];
    __syncthreads();

    int c0 = t, c1 = t + 256;
    float acc[16][2];
#pragma unroll
    for (int r = 0; r < 16; ++r) { acc[r][0] = o1b[c0]; acc[r][1] = o1b[c1]; }
    for (int i = 0; i < 512; ++i) {
        float w0 = o1w[(long)i * 512 + c0], w1 = o1w[(long)i * 512 + c1];
#pragma unroll
        for (int r = 0; r < 16; ++r) {
            float h = hs[r * 512 + i];
            acc[r][0] += h * w0;
            acc[r][1] += h * w1;
        }
    }
    __syncthreads();
#pragma unroll
    for (int r = 0; r < 16; ++r) {
        hs[r * 512 + c0] = fmaxf(acc[r][0], 0.f);
        hs[r * 512 + c1] = fmaxf(acc[r][1], 0.f);
    }
    __syncthreads();

    float acc2[16];
#pragma unroll
    for (int r = 0; r < 16; ++r) acc2[r] = o2b[t];
    for (int i = 0; i < 512; ++i) {
        float w = o2w[(long)i * 256 + t];
#pragma unroll
        for (int r = 0; r < 16; ++r) acc2[r] += hs[r * 512 + i] * w;
    }
    __syncthreads();
#pragma unroll
    for (int r = 0; r < 16; ++r) hs[r * 256 + t] = acc2[r];
    __syncthreads();

    int wave = t >> 6, lane = t & 63;
    for (int rr = 0; rr < 4; ++rr) {
        int r = wave * 4 + rr;
        float v0 = hs[r * 256 + lane];
        float v1 = hs[r * 256 + 64 + lane];
        float v2 = hs[r * 256 + 128 + lane];
        float v3 = hs[r * 256 + 192 + lane];
        float m = fmaxf(fmaxf(v0, v1), fmaxf(v2, v3));
        for (int off = 32; off; off >>= 1) m = fmaxf(m, __shfl_xor(m, off));
        float s = __expf(v0 - m) + __expf(v1 - m) + __expf(v2 - m) + __expf(v3 - m);
        for (int off = 32; off; off >>= 1) s += __shfl_xor(s, off);
        float ls = m + logf(s);
        long ob = (row0 + r) * 256;
        out[ob + lane] = v0 - ls;
        out[ob + 64 + lane] = v1 - ls;
        out[ob + 128 + lane] = v2 - ls;
        out[ob + 192 + lane] = v3 - ls;
    }
}

extern "C" void kernel_launch(void* const* d_in, const int* in_sizes, int n_in,
                              void* d_out, int out_size, void* d_ws, size_t ws_size,
                              hipStream_t stream) {
    const int* x = (const int*)d_in[0];
    const float* mel = (const float*)d_in[1];
    const float* embed_w = (const float*)d_in[2];
    const float* conv_in_w = (const float*)d_in[3];
    const float* conv_in_b = (const float*)d_in[4];
    const float* conv_d1_w = (const float*)d_in[5];
    const float* conv_d1_b = (const float*)d_in[6];
    const float* conv_d2_w = (const float*)d_in[7];
    const float* conv_d2_b = (const float*)d_in[8];
    const float* up1_w = (const float*)d_in[9];
    const float* up1_b = (const float*)d_in[10];
    const float* up2_w = (const float*)d_in[11];
    const float* up2_b = (const float*)d_in[12];
    const float* up3_w = (const float*)d_in[13];
    const float* up3_b = (const float*)d_in[14];
    const float* bn_in_s = (const float*)d_in[15];
    const float* bn_in_o = (const float*)d_in[16];
    const float* bn_d1_s = (const float*)d_in[17];
    const float* bn_d1_o = (const float*)d_in[18];
    const float* bn_d2_s = (const float*)d_in[19];
    const float* bn_d2_o = (const float*)d_in[20];
    const float* bn_u1_s = (const float*)d_in[21];
    const float* bn_u1_o = (const float*)d_in[22];
    const float* bn_u2_s = (const float*)d_in[23];
    const float* bn_u2_o = (const float*)d_in[24];
    const float* bn_u3_s = (const float*)d_in[25];
    const float* bn_u3_o = (const float*)d_in[26];
    const float* gru_wi = (const float*)d_in[27];
    const float* gru_wh = (const float*)d_in[28];
    const float* gru_b = (const float*)d_in[29];
    const float* o1_w = (const float*)d_in[30];
    const float* o1_b = (const float*)d_in[31];
    const float* o2_w = (const float*)d_in[32];
    const float* o2_b = (const float*)d_in[33];

    float* ws = (float*)d_ws;
    float* out = (float*)d_out;

    float* hg = ws + OFF_HG;
    float* rhg = ws + OFF_RHG;
    unsigned* fA = (unsigned*)(ws + OFF_FLA);
    unsigned* fB = (unsigned*)(ws + OFF_FLB);
    float* mean = ws + OFF_MEAN;
    float* scale = ws + OFF_SCALE;
    float* offs = ws + OFF_OFFS;
    float* u0 = ws + OFF_U0;
    float* u0n = ws + OFF_U0N;
    float* r1 = ws + OFF_R1;
    float* u1 = ws + OFF_U1;
    float* r2 = ws + OFF_R2;
    float* u2 = ws + OFF_U2;
    float* y1 = ws + OFF_Y1;
    float* v1 = ws + OFF_V1;
    float* y2 = ws + OFF_Y2;
    float* v2 = ws + OFF_V2;
    float* y3 = ws + OFF_Y3;
    float* cond0 = ws + OFF_COND0;
    float* ewi = ws + OFF_EWI;
    float* cgx = ws + OFF_CGX;
    float* hseq = ws + OFF_HSEQ;

    init_kernel<<<16, 256, 0, stream>>>(hg, rhg, fA, fB);

    // conv_in (K3, rate1) + BN + relu
    conv1d_kernel<<<8 * 38, 512, 240 * 4, stream>>>(mel, conv_in_w, conv_in_b, u0, 40, 38, 80, 3, 1);
    bnstats_kernel<<<512, 64, 0, stream>>>(u0, bn_in_s, bn_in_o, mean, scale, offs, 304, 512);
    bnapply_kernel<<<155648 / 256, 256, 0, stream>>>(u0, u0n, mean, scale, offs, 155648);
    // dilated resblock 1
    conv1d_kernel<<<8 * 36, 512, 1024 * 4, stream>>>(u0n, conv_d1_w, conv_d1_b, r1, 38, 36, 512, 2, 2);
    bnstats_kernel<<<512, 64, 0, stream>>>(r1, bn_d1_s, bn_d1_o, mean, scale, offs, 288, 512);
    bnapply_add_kernel<<<147456 / 256, 256, 0, stream>>>(r1, u0n, u1, mean, scale, offs, 36, 38, 1);
    // dilated resblock 2
    conv1d_kernel<<<8 * 32, 512, 1024 * 4, stream>>>(u1, conv_d2_w, conv_d2_b, r2, 36, 32, 512, 2, 4);
    bnstats_kernel<<<512, 64, 0, stream>>>(r2, bn_d2_s, bn_d2_o, mean, scale, offs, 256, 512);
    bnapply_add_kernel<<<131072 / 256, 256, 0, stream>>>(r2, u1, u2, mean, scale, offs, 32, 36, 2);
    // upsample x2, x2, x4
    tconv1d_kernel<<<8 * 64, 512, 2048, stream>>>(u2, up1_w, up1_b, y1, 32, 2, 512);
    bnstats_kernel<<<512, 64, 0, stream>>>(y1, bn_u1_s, bn_u1_o, mean, scale, offs, 512, 512);
    bnapply_kernel<<<262144 / 256, 256, 0, stream>>>(y1, v1, mean, scale, offs, 262144);
    tconv1d_kernel<<<8 * 128, 512, 2048, stream>>>(v1, up2_w, up2_b, y2, 64, 2, 512);
    bnstats_kernel<<<512, 64, 0, stream>>>(y2, bn_u2_s, bn_u2_o, mean, scale, offs, 1024, 512);
    bnapply_kernel<<<524288 / 256, 256, 0, stream>>>(y2, v2, mean, scale, offs, 524288);
    tconv1d_kernel<<<8 * 512, 512, 2048, stream>>>(v2, up3_w, up3_b, y3, 128, 4, 512);
    bnstats_kernel<<<512, 64, 0, stream>>>(y3, bn_u3_s, bn_u3_o, mean, scale, offs, 4096, 512);
    bnapply_kernel<<<2097152 / 256, 256, 0, stream>>>(y3, cond0, mean, scale, offs, 2097152);

    // collapsed gx: ewi = embed@wi (256x1536), cgx = cond0@wi (4096x1536)
    rowgemm_kernel<<<16, 256, 0, stream>>>(embed_w, gru_wi, ewi, 256);
    rowgemm_kernel<<<256, 256, 0, stream>>>(cond0, gru_wi, cgx, 4096);

    // persistent GRU: 256 wgs, ~104KB dynamic LDS each (1 wg/CU, all co-resident)
    hipFuncSetAttribute(reinterpret_cast<const void*>(gru_kernel),
                        hipFuncAttributeMaxDynamicSharedMemorySize,
                        (int)(GRU_SMEM_FLOATS * sizeof(float)));
    gru_kernel<<<256, 256, GRU_SMEM_FLOATS * sizeof(float), stream>>>(
        gru_wh, gru_b, x, ewi, cgx, hg, rhg, fA, fB, hseq);

    // fused output head + log_softmax
    head_kernel<<<4096, 256, 0, stream>>>(hseq, o1_w, o1_b, o2_w, o2_b, out);
}

// Round 4
// 33680.020 us; speedup vs baseline: 1.2268x; 1.2268x over previous
//
#include <hip/hip_runtime.h>

#define EPSV 1e-5f

#define TAG_LD(p)    __hip_atomic_load((p), __ATOMIC_RELAXED, __HIP_MEMORY_SCOPE_AGENT)
#define TAG_ST(p, v) __hip_atomic_store((p), (v), __ATOMIC_RELAXED, __HIP_MEMORY_SCOPE_AGENT)

// ---------------- workspace layout (float offsets) ----------------
static constexpr long OFF_RHT   = 0;                      // 8*512 ull (tagged rh) = 8192 float slots
static constexpr long OFF_HT    = 8192;                   // 8*512 ull (tagged h)
static constexpr long OFF_MEAN  = 16384;                  // 512
static constexpr long OFF_SCALE = 16896;                  // 512
static constexpr long OFF_OFFS  = 17408;                  // 512
static constexpr long OFF_U0    = 32768;                  // 8*38*512
static constexpr long OFF_U0N   = OFF_U0    + 155648;
static constexpr long OFF_R1    = OFF_U0N   + 155648;     // 8*36*512
static constexpr long OFF_U1    = OFF_R1    + 147456;
static constexpr long OFF_R2    = OFF_U1    + 147456;     // 8*32*512
static constexpr long OFF_U2    = OFF_R2    + 131072;
static constexpr long OFF_Y1    = OFF_U2    + 131072;     // 8*64*512
static constexpr long OFF_V1    = OFF_Y1    + 262144;
static constexpr long OFF_Y2    = OFF_V1    + 262144;     // 8*128*512
static constexpr long OFF_V2    = OFF_Y2    + 524288;
static constexpr long OFF_Y3    = OFF_V2    + 524288;     // 8*512*512
static constexpr long OFF_COND0 = OFF_Y3    + 2097152;
static constexpr long OFF_EWI   = OFF_COND0 + 2097152;    // 256*1536
static constexpr long OFF_CGX   = OFF_EWI   + 393216;     // 4096*1536
static constexpr long OFF_HSEQ  = OFF_CGX   + 6291456;    // 8*8192*512
// total ~46.9M floats (~188 MB)

__global__ void init_kernel(unsigned long long* rhT, unsigned long long* hT) {
    int t = blockIdx.x * 256 + threadIdx.x;
    if (t < 4096) {
        TAG_ST(&rhT[t], 0ull);
        TAG_ST(&hT[t], 0ull);
    }
}

// generic dilated valid conv1d, Cout = blockDim.x
__global__ void conv1d_kernel(const float* __restrict__ in, const float* __restrict__ w,
                              const float* __restrict__ b, float* __restrict__ out,
                              int T_in, int T_out, int Cin, int K, int rate) {
    extern __shared__ float s_in[];
    int n = blockIdx.x / T_out, t = blockIdx.x % T_out;
    int Cout = blockDim.x;
    for (int idx = threadIdx.x; idx < K * Cin; idx += Cout) {
        int k = idx / Cin, i = idx - k * Cin;
        s_in[idx] = in[((long)(n * T_in + t + k * rate)) * Cin + i];
    }
    __syncthreads();
    int c = threadIdx.x;
    float acc = b[c];
    for (int j = 0; j < K * Cin; ++j)
        acc += s_in[j] * w[(long)j * Cout + c];
    out[((long)(n * T_out + t)) * Cout + c] = acc;
}

// conv_transpose, kernel=1, SAME: out[s] = (s%stride==0) ? in[s/stride]@w : 0, + b
__global__ void tconv1d_kernel(const float* __restrict__ in, const float* __restrict__ w,
                               const float* __restrict__ b, float* __restrict__ out,
                               int T_in, int stride, int Cin) {
    extern __shared__ float s_in[];
    int T_out = T_in * stride;
    int n = blockIdx.x / T_out, s = blockIdx.x % T_out;
    int Cout = blockDim.x;
    int c = threadIdx.x;
    if (s % stride) { out[((long)(n * T_out + s)) * Cout + c] = b[c]; return; }
    for (int i = threadIdx.x; i < Cin; i += Cout)
        s_in[i] = in[((long)(n * T_in + s / stride)) * Cin + i];
    __syncthreads();
    float acc = b[c];
    for (int i = 0; i < Cin; ++i) acc += s_in[i] * w[(long)i * Cout + c];
    out[((long)(n * T_out + s)) * Cout + c] = acc;
}

// per-channel batch stats -> mean, scale = s*rsqrt(var+eps), off
__global__ void bnstats_kernel(const float* __restrict__ x, const float* __restrict__ bns,
                               const float* __restrict__ bno, float* mean, float* scale,
                               float* offs, int count, int C) {
    int c = blockIdx.x, t = threadIdx.x;
    float s = 0.f, s2 = 0.f;
    for (int j = t; j < count; j += 64) { float v = x[(long)j * C + c]; s += v; s2 += v * v; }
    for (int off = 32; off; off >>= 1) { s += __shfl_down(s, off); s2 += __shfl_down(s2, off); }
    if (t == 0) {
        float m = s / count;
        float var = s2 / count - m * m;
        mean[c] = m;
        scale[c] = bns[c] * rsqrtf(var + EPSV);
        offs[c] = bno[c];
    }
}

__global__ void bnapply_kernel(const float* __restrict__ x, float* __restrict__ out,
                               const float* mean, const float* scale, const float* offs,
                               long total) {
    long i = (long)blockIdx.x * 256 + threadIdx.x;
    if (i >= total) return;
    int c = (int)(i & 511);
    float v = (x[i] - mean[c]) * scale[c] + offs[c];
    out[i] = fmaxf(v, 0.f);
}

// out[n,t] = base[n, t+shift] + relu(bn(r[n,t]))
__global__ void bnapply_add_kernel(const float* __restrict__ r, const float* __restrict__ base,
                                   float* __restrict__ out, const float* mean, const float* scale,
                                   const float* offs, int T_out, int T_base, int shift) {
    long i = (long)blockIdx.x * 256 + threadIdx.x;
    long total = (long)8 * T_out * 512;
    if (i >= total) return;
    int c = (int)(i & 511);
    long row = i >> 9;
    int n = (int)(row / T_out), t = (int)(row % T_out);
    float v = (r[i] - mean[c]) * scale[c] + offs[c];
    v = fmaxf(v, 0.f);
    out[i] = base[(((long)(n * T_base + t + shift)) << 9) + c] + v;
}

// out[rows x 1536] = A[rows x 512] @ W[512 x 1536]; grid = rows/16, block 256
__global__ void __launch_bounds__(256) rowgemm_kernel(const float* __restrict__ A,
                                                      const float* __restrict__ W,
                                                      float* __restrict__ out, int rows) {
    __shared__ float sA[16 * 512];
    long r0 = (long)blockIdx.x * 16;
    int t = threadIdx.x;
    for (int idx = t; idx < 16 * 512; idx += 256) sA[idx] = A[r0 * 512 + idx];
    __syncthreads();
    float acc[16][6];
#pragma unroll
    for (int r = 0; r < 16; ++r)
#pragma unroll
        for (int j = 0; j < 6; ++j) acc[r][j] = 0.f;
    for (int e = 0; e < 512; ++e) {
        float wv[6];
#pragma unroll
        for (int j = 0; j < 6; ++j) wv[j] = W[(long)e * 1536 + t + 256 * j];
#pragma unroll
        for (int r = 0; r < 16; ++r) {
            float a = sA[r * 512 + e];
#pragma unroll
            for (int j = 0; j < 6; ++j) acc[r][j] += a * wv[j];
        }
    }
    for (int r = 0; r < 16; ++r)
#pragma unroll
        for (int j = 0; j < 6; ++j) out[(r0 + r) * 1536 + t + 256 * j] = acc[r][j];
}

// ---------------- persistent GRU ----------------
// 256 wgs: batch n = blockIdx%8, role = blockIdx/8 (0..31), role owns 16 h-cols.
// Weights (f32) transposed+padded in LDS.
// Cross-WG exchange: TAGGED DATA WORDS. Each published float is an 8B relaxed
// agent-scope atomic (epoch<<32 | float bits) -> flag and payload arrive in
// the same LLC line; consumers spin per-thread directly on the words they
// need. No separate flags, no fences. Overwrite-before-consume is impossible:
// a producer reaches epoch e+1 publication only after passing the opposite
// spin of epoch e, which requires every WG to have consumed epoch e.
#define GRU_SMEM_FLOATS (3 * 16 * 520 + 512 + 512 + 64)

__device__ __forceinline__ float wait_tag(const unsigned long long* p, unsigned ep) {
    unsigned long long v = TAG_LD(p);
    while ((unsigned)(v >> 32) < ep) {
        __builtin_amdgcn_s_sleep(1);
        v = TAG_LD(p);
    }
    union { unsigned u; float f; } c;
    c.u = (unsigned)v;
    return c.f;
}

__global__ void __launch_bounds__(256, 1) gru_kernel(
    const float* __restrict__ wh, const float* __restrict__ gb, const int* __restrict__ x,
    const float* __restrict__ ewi, const float* __restrict__ cgx,
    unsigned long long* __restrict__ rhT, unsigned long long* __restrict__ hT,
    float* __restrict__ hseq) {
    extern __shared__ float sm[];
    float* Wzt = sm;                    // [16][520]
    float* Wrt = Wzt + 16 * 520;
    float* Wat = Wrt + 16 * 520;
    float* h_l = Wat + 16 * 520;        // [512]
    float* rh_l = h_l + 512;            // [512]
    float* bz = rh_l + 512;             // [16]*3
    float* br = bz + 16;
    float* ba = br + 16;

    int wg = blockIdx.x;
    int n = wg & 7;
    int role = wg >> 3;
    int base = role * 16;
    int t = threadIdx.x;

    for (int idx = t; idx < 512 * 16; idx += 256) {
        int i = idx >> 4, c = idx & 15;
        Wzt[c * 520 + i] = wh[(long)i * 1536 + base + c];
        Wrt[c * 520 + i] = wh[(long)i * 1536 + 512 + base + c];
        Wat[c * 520 + i] = wh[(long)i * 1536 + 1024 + base + c];
    }
    if (t < 16) { bz[t] = gb[base + t]; br[t] = gb[512 + base + t]; ba[t] = gb[1024 + base + t]; }
    // initial h = 0
    h_l[t] = 0.f;
    h_l[t + 256] = 0.f;
    __syncthreads();

    const float* cgxn = cgx + (long)n * 512 * 1536;
    unsigned long long* rhTn = rhT + n * 512;
    unsigned long long* hTn = hT + n * 512;

    int col = t >> 4, sub = t & 15;
    const float* Wz_c = Wzt + col * 520;
    const float* Wr_c = Wrt + col * 520;
    const float* Wa_c = Wat + col * 520;

    int c0 = t, c1 = t + 256;
    bool own0 = (c0 >= base) && (c0 < base + 16);
    bool own1 = (c1 >= base) && (c1 < base + 16);

    // prefetch gate inputs for step 0 (producer lanes only)
    float gz = 0.f, gr = 0.f, ga = 0.f;
    if (sub == 0) {
        int xv = x[n * 8192];
        const float* e_row = ewi + (long)xv * 1536;
        const float* c_row = cgxn;
        gz = e_row[base + col] + c_row[base + col] + bz[col];
        gr = e_row[512 + base + col] + c_row[512 + base + col] + br[col];
        ga = e_row[1024 + base + col] + c_row[1024 + base + col] + ba[col];
    }

    for (int l = 0; l < 8192; ++l) {
        unsigned ep = (unsigned)(l + 1);

        // ---- phase A: r matvec, publish tagged rh ASAP ----
        float accr = 0.f;
#pragma unroll 8
        for (int k = 0; k < 32; ++k) {
            int i = sub + (k << 4);
            accr += h_l[i] * Wr_c[i];
        }
        accr += __shfl_down(accr, 8, 16);
        accr += __shfl_down(accr, 4, 16);
        accr += __shfl_down(accr, 2, 16);
        accr += __shfl_down(accr, 1, 16);
        if (sub == 0) {
            float rr = 1.f / (1.f + __expf(-(gr + accr)));
            float rhv = rr * h_l[base + col];
            rh_l[base + col] = rhv;                              // own cols local
            TAG_ST(&rhTn[base + col],
                   ((unsigned long long)ep << 32) | (unsigned long long)__float_as_uint(rhv));
        }

        // ---- overlap: z matvec while others finish phase A ----
        float accz = 0.f;
#pragma unroll 8
        for (int k = 0; k < 32; ++k) {
            int i = sub + (k << 4);
            accz += h_l[i] * Wz_c[i];
        }
        accz += __shfl_down(accz, 8, 16);
        accz += __shfl_down(accz, 4, 16);
        accz += __shfl_down(accz, 2, 16);
        accz += __shfl_down(accz, 1, 16);
        float z = (sub == 0) ? 1.f / (1.f + __expf(-(gz + accz))) : 0.f;

        // ---- spin on tagged rh (data+flag in one word) ----
        if (!own0) rh_l[c0] = wait_tag(&rhTn[c0], ep);
        if (!own1) rh_l[c1] = wait_tag(&rhTn[c1], ep);
        __syncthreads();

        // ---- phase B: a matvec + h update, publish tagged h ----
        float acca = 0.f;
#pragma unroll 8
        for (int k = 0; k < 32; ++k) {
            int i = sub + (k << 4);
            acca += rh_l[i] * Wa_c[i];
        }
        acca += __shfl_down(acca, 8, 16);
        acca += __shfl_down(acca, 4, 16);
        acca += __shfl_down(acca, 2, 16);
        acca += __shfl_down(acca, 1, 16);
        if (sub == 0) {
            float pre = ga + acca;
            float axv = fabsf(pre);
            float ex = __expf(-2.f * axv);
            float th = (1.f - ex) / (1.f + ex);
            float a = copysignf(th, pre);
            float hn = (1.f - z) * h_l[base + col] + z * a;
            h_l[base + col] = hn;                                // own cols local
            if (l != 8191)
                TAG_ST(&hTn[base + col],
                       ((unsigned long long)ep << 32) | (unsigned long long)__float_as_uint(hn));
            hseq[(((long)n * 8192 + l) << 9) + base + col] = hn;
        }
        if (l == 8191) break;

        // ---- prefetch next step's gate inputs (hides under h-spin) ----
        if (sub == 0) {
            int xv = x[n * 8192 + l + 1];
            const float* e_row = ewi + (long)xv * 1536;
            const float* c_row = cgxn + (long)((l + 1) >> 4) * 1536;
            gz = e_row[base + col] + c_row[base + col] + bz[col];
            gr = e_row[512 + base + col] + c_row[512 + base + col] + br[col];
            ga = e_row[1024 + base + col] + c_row[1024 + base + col] + ba[col];
        }

        // ---- spin on tagged h ----
        if (!own0) h_l[c0] = wait_tag(&hTn[c0], ep);
        if (!own1) h_l[c1] = wait_tag(&hTn[c1], ep);
        __syncthreads();
    }
}

// fused head: relu(h@o1+b1)@o2+b2 -> log_softmax; 16 rows per block
__global__ void __launch_bounds__(256) head_kernel(const float* __restrict__ hseq,
                                                   const float* __restrict__ o1w,
                                                   const float* __restrict__ o1b,
                                                   const float* __restrict__ o2w,
                                                   const float* __restrict__ o2b,
                                                   float* __restrict__ out) {
    __shared__ float hs[16 * 512];
    long row0 = (long)blockIdx.x * 16;
    int t = threadIdx.x;
    for (int idx = t; idx < 16 * 512; idx += 256) hs[idx] = hseq[row0 * 512 + idx];
    __syncthreads();

    int c0 = t, c1 = t + 256;
    float acc[16][2];
#pragma unroll
    for (int r = 0; r < 16; ++r) { acc[r][0] = o1b[c0]; acc[r][1] = o1b[c1]; }
    for (int i = 0; i < 512; ++i) {
        float w0 = o1w[(long)i * 512 + c0], w1 = o1w[(long)i * 512 + c1];
#pragma unroll
        for (int r = 0; r < 16; ++r) {
            float h = hs[r * 512 + i];
            acc[r][0] += h * w0;
            acc[r][1] += h * w1;
        }
    }
    __syncthreads();
#pragma unroll
    for (int r = 0; r < 16; ++r) {
        hs[r * 512 + c0] = fmaxf(acc[r][0], 0.f);
        hs[r * 512 + c1] = fmaxf(acc[r][1], 0.f);
    }
    __syncthreads();

    float acc2[16];
#pragma unroll
    for (int r = 0; r < 16; ++r) acc2[r] = o2b[t];
    for (int i = 0; i < 512; ++i) {
        float w = o2w[(long)i * 256 + t];
#pragma unroll
        for (int r = 0; r < 16; ++r) acc2[r] += hs[r * 512 + i] * w;
    }
    __syncthreads();
#pragma unroll
    for (int r = 0; r < 16; ++r) hs[r * 256 + t] = acc2[r];
    __syncthreads();

    int wave = t >> 6, lane = t & 63;
    for (int rr = 0; rr < 4; ++rr) {
        int r = wave * 4 + rr;
        float v0 = hs[r * 256 + lane];
        float v1 = hs[r * 256 + 64 + lane];
        float v2 = hs[r * 256 + 128 + lane];
        float v3 = hs[r * 256 + 192 + lane];
        float m = fmaxf(fmaxf(v0, v1), fmaxf(v2, v3));
        for (int off = 32; off; off >>= 1) m = fmaxf(m, __shfl_xor(m, off));
        float s = __expf(v0 - m) + __expf(v1 - m) + __expf(v2 - m) + __expf(v3 - m);
        for (int off = 32; off; off >>= 1) s += __shfl_xor(s, off);
        float ls = m + logf(s);
        long ob = (row0 + r) * 256;
        out[ob + lane] = v0 - ls;
        out[ob + 64 + lane] = v1 - ls;
        out[ob + 128 + lane] = v2 - ls;
        out[ob + 192 + lane] = v3 - ls;
    }
}

extern "C" void kernel_launch(void* const* d_in, const int* in_sizes, int n_in,
                              void* d_out, int out_size, void* d_ws, size_t ws_size,
                              hipStream_t stream) {
    const int* x = (const int*)d_in[0];
    const float* mel = (const float*)d_in[1];
    const float* embed_w = (const float*)d_in[2];
    const float* conv_in_w = (const float*)d_in[3];
    const float* conv_in_b = (const float*)d_in[4];
    const float* conv_d1_w = (const float*)d_in[5];
    const float* conv_d1_b = (const float*)d_in[6];
    const float* conv_d2_w = (const float*)d_in[7];
    const float* conv_d2_b = (const float*)d_in[8];
    const float* up1_w = (const float*)d_in[9];
    const float* up1_b = (const float*)d_in[10];
    const float* up2_w = (const float*)d_in[11];
    const float* up2_b = (const float*)d_in[12];
    const float* up3_w = (const float*)d_in[13];
    const float* up3_b = (const float*)d_in[14];
    const float* bn_in_s = (const float*)d_in[15];
    const float* bn_in_o = (const float*)d_in[16];
    const float* bn_d1_s = (const float*)d_in[17];
    const float* bn_d1_o = (const float*)d_in[18];
    const float* bn_d2_s = (const float*)d_in[19];
    const float* bn_d2_o = (const float*)d_in[20];
    const float* bn_u1_s = (const float*)d_in[21];
    const float* bn_u1_o = (const float*)d_in[22];
    const float* bn_u2_s = (const float*)d_in[23];
    const float* bn_u2_o = (const float*)d_in[24];
    const float* bn_u3_s = (const float*)d_in[25];
    const float* bn_u3_o = (const float*)d_in[26];
    const float* gru_wi = (const float*)d_in[27];
    const float* gru_wh = (const float*)d_in[28];
    const float* gru_b = (const float*)d_in[29];
    const float* o1_w = (const float*)d_in[30];
    const float* o1_b = (const float*)d_in[31];
    const float* o2_w = (const float*)d_in[32];
    const float* o2_b = (const float*)d_in[33];

    float* ws = (float*)d_ws;
    float* out = (float*)d_out;

    unsigned long long* rhT = (unsigned long long*)(ws + OFF_RHT);
    unsigned long long* hT = (unsigned long long*)(ws + OFF_HT);
    float* mean = ws + OFF_MEAN;
    float* scale = ws + OFF_SCALE;
    float* offs = ws + OFF_OFFS;
    float* u0 = ws + OFF_U0;
    float* u0n = ws + OFF_U0N;
    float* r1 = ws + OFF_R1;
    float* u1 = ws + OFF_U1;
    float* r2 = ws + OFF_R2;
    float* u2 = ws + OFF_U2;
    float* y1 = ws + OFF_Y1;
    float* v1 = ws + OFF_V1;
    float* y2 = ws + OFF_Y2;
    float* v2 = ws + OFF_V2;
    float* y3 = ws + OFF_Y3;
    float* cond0 = ws + OFF_COND0;
    float* ewi = ws + OFF_EWI;
    float* cgx = ws + OFF_CGX;
    float* hseq = ws + OFF_HSEQ;

    init_kernel<<<16, 256, 0, stream>>>(rhT, hT);

    // conv_in (K3, rate1) + BN + relu
    conv1d_kernel<<<8 * 38, 512, 240 * 4, stream>>>(mel, conv_in_w, conv_in_b, u0, 40, 38, 80, 3, 1);
    bnstats_kernel<<<512, 64, 0, stream>>>(u0, bn_in_s, bn_in_o, mean, scale, offs, 304, 512);
    bnapply_kernel<<<155648 / 256, 256, 0, stream>>>(u0, u0n, mean, scale, offs, 155648);
    // dilated resblock 1
    conv1d_kernel<<<8 * 36, 512, 1024 * 4, stream>>>(u0n, conv_d1_w, conv_d1_b, r1, 38, 36, 512, 2, 2);
    bnstats_kernel<<<512, 64, 0, stream>>>(r1, bn_d1_s, bn_d1_o, mean, scale, offs, 288, 512);
    bnapply_add_kernel<<<147456 / 256, 256, 0, stream>>>(r1, u0n, u1, mean, scale, offs, 36, 38, 1);
    // dilated resblock 2
    conv1d_kernel<<<8 * 32, 512, 1024 * 4, stream>>>(u1, conv_d2_w, conv_d2_b, r2, 36, 32, 512, 2, 4);
    bnstats_kernel<<<512, 64, 0, stream>>>(r2, bn_d2_s, bn_d2_o, mean, scale, offs, 256, 512);
    bnapply_add_kernel<<<131072 / 256, 256, 0, stream>>>(r2, u1, u2, mean, scale, offs, 32, 36, 2);
    // upsample x2, x2, x4
    tconv1d_kernel<<<8 * 64, 512, 2048, stream>>>(u2, up1_w, up1_b, y1, 32, 2, 512);
    bnstats_kernel<<<512, 64, 0, stream>>>(y1, bn_u1_s, bn_u1_o, mean, scale, offs, 512, 512);
    bnapply_kernel<<<262144 / 256, 256, 0, stream>>>(y1, v1, mean, scale, offs, 262144);
    tconv1d_kernel<<<8 * 128, 512, 2048, stream>>>(v1, up2_w, up2_b, y2, 64, 2, 512);
    bnstats_kernel<<<512, 64, 0, stream>>>(y2, bn_u2_s, bn_u2_o, mean, scale, offs, 1024, 512);
    bnapply_kernel<<<524288 / 256, 256, 0, stream>>>(y2, v2, mean, scale, offs, 524288);
    tconv1d_kernel<<<8 * 512, 512, 2048, stream>>>(v2, up3_w, up3_b, y3, 128, 4, 512);
    bnstats_kernel<<<512, 64, 0, stream>>>(y3, bn_u3_s, bn_u3_o, mean, scale, offs, 4096, 512);
    bnapply_kernel<<<2097152 / 256, 256, 0, stream>>>(y3, cond0, mean, scale, offs, 2097152);

    // collapsed gx: ewi = embed@wi (256x1536), cgx = cond0@wi (4096x1536)
    rowgemm_kernel<<<16, 256, 0, stream>>>(embed_w, gru_wi, ewi, 256);
    rowgemm_kernel<<<256, 256, 0, stream>>>(cond0, gru_wi, cgx, 4096);

    // persistent GRU: 256 wgs, ~104KB dynamic LDS each (1 wg/CU, all co-resident)
    hipFuncSetAttribute(reinterpret_cast<const void*>(gru_kernel),
                        hipFuncAttributeMaxDynamicSharedMemorySize,
                        (int)(GRU_SMEM_FLOATS * sizeof(float)));
    gru_kernel<<<256, 256, GRU_SMEM_FLOATS * sizeof(float), stream>>>(
        gru_wh, gru_b, x, ewi, cgx, rhT, hT, hseq);

    // fused output head + log_softmax
    head_kernel<<<4096, 256, 0, stream>>>(hseq, o1_w, o1_b, o2_w, o2_b, out);
}

// Round 6
// 23912.224 us; speedup vs baseline: 1.7279x; 1.4085x over previous
//
#include <hip/hip_runtime.h>

#define EPSV 1e-5f

#define AT_LD(p)    __hip_atomic_load((p), __ATOMIC_RELAXED, __HIP_MEMORY_SCOPE_AGENT)
#define AT_ST(p, v) __hip_atomic_store((p), (v), __ATOMIC_RELAXED, __HIP_MEMORY_SCOPE_AGENT)

// ---------------- workspace layout (float offsets) ----------------
static constexpr long OFF_FRH   = 0;                      // 8*512 ull fast rh (XCD-L2 lane)
static constexpr long OFF_FH    = 8192;                   // 8*512 ull fast h
static constexpr long OFF_SRH   = 16384;                  // 8*512 ull slow rh (LLC lane)
static constexpr long OFF_SH    = 24576;                  // 8*512 ull slow h
static constexpr long OFF_BAR   = 32768;                  // 1 uint barrier
static constexpr long OFF_MEAN  = 33280;                  // 512
static constexpr long OFF_SCALE = 33792;                  // 512
static constexpr long OFF_OFFS  = 34304;                  // 512
static constexpr long OFF_U0    = 40960;                  // 8*38*512
static constexpr long OFF_U0N   = OFF_U0    + 155648;
static constexpr long OFF_R1    = OFF_U0N   + 155648;     // 8*36*512
static constexpr long OFF_U1    = OFF_R1    + 147456;
static constexpr long OFF_R2    = OFF_U1    + 147456;     // 8*32*512
static constexpr long OFF_U2    = OFF_R2    + 131072;
static constexpr long OFF_Y1    = OFF_U2    + 131072;     // 8*64*512
static constexpr long OFF_V1    = OFF_Y1    + 262144;
static constexpr long OFF_Y2    = OFF_V1    + 262144;     // 8*128*512
static constexpr long OFF_V2    = OFF_Y2    + 524288;
static constexpr long OFF_Y3    = OFF_V2    + 524288;     // 8*512*512
static constexpr long OFF_COND0 = OFF_Y3    + 2097152;
static constexpr long OFF_EWI   = OFF_COND0 + 2097152;    // 256*1536
static constexpr long OFF_CGX   = OFF_EWI   + 393216;     // 4096*1536
static constexpr long OFF_HSEQ  = OFF_CGX   + 6291456;    // 8*8192*512

// zero all 4 tagged buffers (LLC) + barrier; per-XCD L2 hygiene is done
// inside gru_kernel via plain-store sweeps.
__global__ void init_kernel(unsigned long long* tagbase, unsigned* bar) {
    int t = blockIdx.x * 256 + threadIdx.x;
    if (t < 16384) AT_ST(&tagbase[t], 0ull);
    if (t == 0) AT_ST(bar, 0u);
}

// generic dilated valid conv1d, Cout = blockDim.x
__global__ void conv1d_kernel(const float* __restrict__ in, const float* __restrict__ w,
                              const float* __restrict__ b, float* __restrict__ out,
                              int T_in, int T_out, int Cin, int K, int rate) {
    extern __shared__ float s_in[];
    int n = blockIdx.x / T_out, t = blockIdx.x % T_out;
    int Cout = blockDim.x;
    for (int idx = threadIdx.x; idx < K * Cin; idx += Cout) {
        int k = idx / Cin, i = idx - k * Cin;
        s_in[idx] = in[((long)(n * T_in + t + k * rate)) * Cin + i];
    }
    __syncthreads();
    int c = threadIdx.x;
    float acc = b[c];
    for (int j = 0; j < K * Cin; ++j)
        acc += s_in[j] * w[(long)j * Cout + c];
    out[((long)(n * T_out + t)) * Cout + c] = acc;
}

// conv_transpose, kernel=1, SAME
__global__ void tconv1d_kernel(const float* __restrict__ in, const float* __restrict__ w,
                               const float* __restrict__ b, float* __restrict__ out,
                               int T_in, int stride, int Cin) {
    extern __shared__ float s_in[];
    int T_out = T_in * stride;
    int n = blockIdx.x / T_out, s = blockIdx.x % T_out;
    int Cout = blockDim.x;
    int c = threadIdx.x;
    if (s % stride) { out[((long)(n * T_out + s)) * Cout + c] = b[c]; return; }
    for (int i = threadIdx.x; i < Cin; i += Cout)
        s_in[i] = in[((long)(n * T_in + s / stride)) * Cin + i];
    __syncthreads();
    float acc = b[c];
    for (int i = 0; i < Cin; ++i) acc += s_in[i] * w[(long)i * Cout + c];
    out[((long)(n * T_out + s)) * Cout + c] = acc;
}

__global__ void bnstats_kernel(const float* __restrict__ x, const float* __restrict__ bns,
                               const float* __restrict__ bno, float* mean, float* scale,
                               float* offs, int count, int C) {
    int c = blockIdx.x, t = threadIdx.x;
    float s = 0.f, s2 = 0.f;
    for (int j = t; j < count; j += 64) { float v = x[(long)j * C + c]; s += v; s2 += v * v; }
    for (int off = 32; off; off >>= 1) { s += __shfl_down(s, off); s2 += __shfl_down(s2, off); }
    if (t == 0) {
        float m = s / count;
        float var = s2 / count - m * m;
        mean[c] = m;
        scale[c] = bns[c] * rsqrtf(var + EPSV);
        offs[c] = bno[c];
    }
}

__global__ void bnapply_kernel(const float* __restrict__ x, float* __restrict__ out,
                               const float* mean, const float* scale, const float* offs,
                               long total) {
    long i = (long)blockIdx.x * 256 + threadIdx.x;
    if (i >= total) return;
    int c = (int)(i & 511);
    float v = (x[i] - mean[c]) * scale[c] + offs[c];
    out[i] = fmaxf(v, 0.f);
}

__global__ void bnapply_add_kernel(const float* __restrict__ r, const float* __restrict__ base,
                                   float* __restrict__ out, const float* mean, const float* scale,
                                   const float* offs, int T_out, int T_base, int shift) {
    long i = (long)blockIdx.x * 256 + threadIdx.x;
    long total = (long)8 * T_out * 512;
    if (i >= total) return;
    int c = (int)(i & 511);
    long row = i >> 9;
    int n = (int)(row / T_out), t = (int)(row % T_out);
    float v = (r[i] - mean[c]) * scale[c] + offs[c];
    v = fmaxf(v, 0.f);
    out[i] = base[(((long)(n * T_base + t + shift)) << 9) + c] + v;
}

// out[rows x 1536] = A[rows x 512] @ W[512 x 1536]
__global__ void __launch_bounds__(256) rowgemm_kernel(const float* __restrict__ A,
                                                      const float* __restrict__ W,
                                                      float* __restrict__ out, int rows) {
    __shared__ float sA[16 * 512];
    long r0 = (long)blockIdx.x * 16;
    int t = threadIdx.x;
    for (int idx = t; idx < 16 * 512; idx += 256) sA[idx] = A[r0 * 512 + idx];
    __syncthreads();
    float acc[16][6];
#pragma unroll
    for (int r = 0; r < 16; ++r)
#pragma unroll
        for (int j = 0; j < 6; ++j) acc[r][j] = 0.f;
    for (int e = 0; e < 512; ++e) {
        float wv[6];
#pragma unroll
        for (int j = 0; j < 6; ++j) wv[j] = W[(long)e * 1536 + t + 256 * j];
#pragma unroll
        for (int r = 0; r < 16; ++r) {
            float a = sA[r * 512 + e];
#pragma unroll
            for (int j = 0; j < 6; ++j) acc[r][j] += a * wv[j];
        }
    }
    for (int r = 0; r < 16; ++r)
#pragma unroll
        for (int j = 0; j < 6; ++j) out[(r0 + r) * 1536 + t + 256 * j] = acc[r][j];
}

// ---------------- persistent GRU ----------------
// 256 wgs x 512 threads: batch n = blockIdx%8, role = blockIdx/8 owns 16 cols.
// Exchange = 8B tagged words (epoch<<32|f32), DUAL-PUBLISHED:
//   fast lane: plain store -> producer's XCD L2; poll = sc0 load (bypass L0).
//   slow lane: relaxed agent atomic -> LLC (R4-proven, ALWAYS written).
// Consumer: bounded fast poll (8 tries) then guaranteed slow poll ->
// deadlock-free by construction regardless of placement or cache semantics.
// Sticky per-thread fallback after 4 fast misses. Every WG plain-store sweeps
// ALL fast words of its batch (dirty-0 its own L2 -> no stale false-accepts);
// owners sweep slow words. Start barrier is iteration-BOUNDED (no hang).
#define GRU_SMEM_FLOATS (3 * 16 * 520 + 512 + 512 + 48)

__device__ __forceinline__ unsigned long long fast_ld(const unsigned long long* p) {
    unsigned long long v;
    asm volatile("global_load_dwordx2 %0, %1, off sc0\n\ts_waitcnt vmcnt(0)"
                 : "=&v"(v) : "v"(p) : "memory");
    return v;
}

__device__ __forceinline__ void pub_word(unsigned long long* fp, unsigned long long* sp,
                                         unsigned ep, float val) {
    unsigned long long w = ((unsigned long long)ep << 32) | (unsigned long long)__float_as_uint(val);
    *fp = w;        // plain store: write-through to local XCD L2
    AT_ST(sp, w);   // agent store: LLC (guaranteed lane)
}

__device__ __forceinline__ float wait_word(const unsigned long long* fp,
                                           const unsigned long long* sp,
                                           unsigned ep, int& fails) {
    if (fails < 4) {
#pragma unroll 1
        for (int k = 0; k < 8; ++k) {
            unsigned long long v = fast_ld(fp);
            if ((unsigned)(v >> 32) >= ep)
                return __uint_as_float((unsigned)(v & 0xFFFFFFFFull));
        }
        ++fails;
    }
    unsigned long long v = AT_LD(sp);
    while ((unsigned)(v >> 32) < ep) {
        __builtin_amdgcn_s_sleep(1);
        v = AT_LD(sp);
    }
    return __uint_as_float((unsigned)(v & 0xFFFFFFFFull));
}

__global__ void __launch_bounds__(512, 1) gru_kernel(
    const float* __restrict__ wh, const float* __restrict__ gb, const int* __restrict__ x,
    const float* __restrict__ ewi, const float* __restrict__ cgx,
    unsigned long long* __restrict__ fRH, unsigned long long* __restrict__ fH,
    unsigned long long* __restrict__ sRH, unsigned long long* __restrict__ sH,
    unsigned* __restrict__ bar, float* __restrict__ hseq) {
    extern __shared__ float sm[];
    float* Wzt = sm;                    // [16][520]
    float* Wrt = Wzt + 16 * 520;
    float* Wat = Wrt + 16 * 520;
    float* h_l = Wat + 16 * 520;        // [512]
    float* rh_l = h_l + 512;            // [512]
    float* bz = rh_l + 512;             // [16]*3
    float* br = bz + 16;
    float* ba = br + 16;

    int wg = blockIdx.x;
    int n = wg & 7;
    int role = wg >> 3;
    int base = role * 16;
    int t = threadIdx.x;

    unsigned long long* fRHn = fRH + n * 512;
    unsigned long long* fHn = fH + n * 512;
    unsigned long long* sRHn = sRH + n * 512;
    unsigned long long* sHn = sH + n * 512;

    // weights + biases to LDS
    for (int idx = t; idx < 512 * 16; idx += 512) {
        int i = idx >> 4, c = idx & 15;
        Wzt[c * 520 + i] = wh[(long)i * 1536 + base + c];
        Wrt[c * 520 + i] = wh[(long)i * 1536 + 512 + base + c];
        Wat[c * 520 + i] = wh[(long)i * 1536 + 1024 + base + c];
    }
    if (t < 16) { bz[t] = gb[base + t]; br[t] = gb[512 + base + t]; ba[t] = gb[1024 + base + t]; }
    h_l[t] = 0.f;

    // sweep: dirty-0 ALL fast words of this batch into OUR L2 (stale-proof),
    // owners zero their slow words at the LLC.
    bool own = ((t >> 4) == role);
    fRHn[t] = 0ull;
    fHn[t] = 0ull;
    if (own) { AT_ST(&sRHn[t], 0ull); AT_ST(&sHn[t], 0ull); }
    asm volatile("s_waitcnt vmcnt(0)" ::: "memory");
    __syncthreads();
    // bounded grid barrier (liveness-safe: protocol stays correct even if it expires)
    if (t == 0) {
        __hip_atomic_fetch_add(bar, 1u, __ATOMIC_RELAXED, __HIP_MEMORY_SCOPE_AGENT);
        for (int it = 0; it < 20000000; ++it) {
            if (AT_LD(bar) >= 256u) break;
            __builtin_amdgcn_s_sleep(2);
        }
    }
    __syncthreads();

    const float* cgxn = cgx + (long)n * 512 * 1536;
    int col = t >> 5, sub = t & 31;      // 16 cols x 32 lanes
    const float* Wz_c = Wzt + col * 520;
    const float* Wr_c = Wrt + col * 520;
    const float* Wa_c = Wat + col * 520;

    int fails = 0;

    // prefetch gate inputs for step 0 (producer lanes only)
    float gz = 0.f, gr = 0.f, ga = 0.f;
    if (sub == 0) {
        int xv = x[n * 8192];
        const float* e_row = ewi + (long)xv * 1536;
        gz = e_row[base + col] + cgxn[base + col] + bz[col];
        gr = e_row[512 + base + col] + cgxn[512 + base + col] + br[col];
        ga = e_row[1024 + base + col] + cgxn[1024 + base + col] + ba[col];
    }

    for (int l = 0; l < 8192; ++l) {
        unsigned ep = (unsigned)(l + 1);

        // ---- phase A: r matvec, publish tagged rh ASAP ----
        float accr = 0.f;
#pragma unroll
        for (int k = 0; k < 16; ++k) {
            int i = sub + (k << 5);
            accr += h_l[i] * Wr_c[i];
        }
        accr += __shfl_down(accr, 16, 32);
        accr += __shfl_down(accr, 8, 32);
        accr += __shfl_down(accr, 4, 32);
        accr += __shfl_down(accr, 2, 32);
        accr += __shfl_down(accr, 1, 32);
        if (sub == 0) {
            float rr = 1.f / (1.f + __expf(-(gr + accr)));
            float rhv = rr * h_l[base + col];
            rh_l[base + col] = rhv;
            pub_word(&fRHn[base + col], &sRHn[base + col], ep, rhv);
        }

        // ---- overlap: z matvec while others finish phase A ----
        float accz = 0.f;
#pragma unroll
        for (int k = 0; k < 16; ++k) {
            int i = sub + (k << 5);
            accz += h_l[i] * Wz_c[i];
        }
        accz += __shfl_down(accz, 16, 32);
        accz += __shfl_down(accz, 8, 32);
        accz += __shfl_down(accz, 4, 32);
        accz += __shfl_down(accz, 2, 32);
        accz += __shfl_down(accz, 1, 32);
        float z = (sub == 0) ? 1.f / (1.f + __expf(-(gz + accz))) : 0.f;

        // ---- wait on tagged rh (fast L2 lane, slow LLC fallback) ----
        if (!own) rh_l[t] = wait_word(&fRHn[t], &sRHn[t], ep, fails);
        __syncthreads();

        // ---- phase B: a matvec + h update, publish tagged h ----
        float acca = 0.f;
#pragma unroll
        for (int k = 0; k < 16; ++k) {
            int i = sub + (k << 5);
            acca += rh_l[i] * Wa_c[i];
        }
        acca += __shfl_down(acca, 16, 32);
        acca += __shfl_down(acca, 8, 32);
        acca += __shfl_down(acca, 4, 32);
        acca += __shfl_down(acca, 2, 32);
        acca += __shfl_down(acca, 1, 32);
        if (sub == 0) {
            float pre = ga + acca;
            float axv = fabsf(pre);
            float ex = __expf(-2.f * axv);
            float th = (1.f - ex) / (1.f + ex);
            float a = copysignf(th, pre);
            float hn = (1.f - z) * h_l[base + col] + z * a;
            h_l[base + col] = hn;
            if (l != 8191) pub_word(&fHn[base + col], &sHn[base + col], ep, hn);
            hseq[(((long)n * 8192 + l) << 9) + base + col] = hn;
        }
        if (l == 8191) break;

        // ---- prefetch next step's gate inputs (hides under h-wait) ----
        if (sub == 0) {
            int xv = x[n * 8192 + l + 1];
            const float* e_row = ewi + (long)xv * 1536;
            const float* c_row = cgxn + (long)((l + 1) >> 4) * 1536;
            gz = e_row[base + col] + c_row[base + col] + bz[col];
            gr = e_row[512 + base + col] + c_row[512 + base + col] + br[col];
            ga = e_row[1024 + base + col] + c_row[1024 + base + col] + ba[col];
        }

        // ---- wait on tagged h ----
        if (!own) h_l[t] = wait_word(&fHn[t], &sHn[t], ep, fails);
        __syncthreads();
    }
}

// fused head: relu(h@o1+b1)@o2+b2 -> log_softmax; 16 rows per block
__global__ void __launch_bounds__(256) head_kernel(const float* __restrict__ hseq,
                                                   const float* __restrict__ o1w,
                                                   const float* __restrict__ o1b,
                                                   const float* __restrict__ o2w,
                                                   const float* __restrict__ o2b,
                                                   float* __restrict__ out) {
    __shared__ float hs[16 * 512];
    long row0 = (long)blockIdx.x * 16;
    int t = threadIdx.x;
    for (int idx = t; idx < 16 * 512; idx += 256) hs[idx] = hseq[row0 * 512 + idx];
    __syncthreads();

    int c0 = t, c1 = t + 256;
    float acc[16][2];
#pragma unroll
    for (int r = 0; r < 16; ++r) { acc[r][0] = o1b[c0]; acc[r][1] = o1b[c1]; }
    for (int i = 0; i < 512; ++i) {
        float w0 = o1w[(long)i * 512 + c0], w1 = o1w[(long)i * 512 + c1];
#pragma unroll
        for (int r = 0; r < 16; ++r) {
            float h = hs[r * 512 + i];
            acc[r][0] += h * w0;
            acc[r][1] += h * w1;
        }
    }
    __syncthreads();
#pragma unroll
    for (int r = 0; r < 16; ++r) {
        hs[r * 512 + c0] = fmaxf(acc[r][0], 0.f);
        hs[r * 512 + c1] = fmaxf(acc[r][1], 0.f);
    }
    __syncthreads();

    float acc2[16];
#pragma unroll
    for (int r = 0; r < 16; ++r) acc2[r] = o2b[t];
    for (int i = 0; i < 512; ++i) {
        float w = o2w[(long)i * 256 + t];
#pragma unroll
        for (int r = 0; r < 16; ++r) acc2[r] += hs[r * 512 + i] * w;
    }
    __syncthreads();
#pragma unroll
    for (int r = 0; r < 16; ++r) hs[r * 256 + t] = acc2[r];
    __syncthreads();

    int wave = t >> 6, lane = t & 63;
    for (int rr = 0; rr < 4; ++rr) {
        int r = wave * 4 + rr;
        float v0 = hs[r * 256 + lane];
        float v1 = hs[r * 256 + 64 + lane];
        float v2 = hs[r * 256 + 128 + lane];
        float v3 = hs[r * 256 + 192 + lane];
        float m = fmaxf(fmaxf(v0, v1), fmaxf(v2, v3));
        for (int off = 32; off; off >>= 1) m = fmaxf(m, __shfl_xor(m, off));
        float s = __expf(v0 - m) + __expf(v1 - m) + __expf(v2 - m) + __expf(v3 - m);
        for (int off = 32; off; off >>= 1) s += __shfl_xor(s, off);
        float ls = m + logf(s);
        long ob = (row0 + r) * 256;
        out[ob + lane] = v0 - ls;
        out[ob + 64 + lane] = v1 - ls;
        out[ob + 128 + lane] = v2 - ls;
        out[ob + 192 + lane] = v3 - ls;
    }
}

extern "C" void kernel_launch(void* const* d_in, const int* in_sizes, int n_in,
                              void* d_out, int out_size, void* d_ws, size_t ws_size,
                              hipStream_t stream) {
    const int* x = (const int*)d_in[0];
    const float* mel = (const float*)d_in[1];
    const float* embed_w = (const float*)d_in[2];
    const float* conv_in_w = (const float*)d_in[3];
    const float* conv_in_b = (const float*)d_in[4];
    const float* conv_d1_w = (const float*)d_in[5];
    const float* conv_d1_b = (const float*)d_in[6];
    const float* conv_d2_w = (const float*)d_in[7];
    const float* conv_d2_b = (const float*)d_in[8];
    const float* up1_w = (const float*)d_in[9];
    const float* up1_b = (const float*)d_in[10];
    const float* up2_w = (const float*)d_in[11];
    const float* up2_b = (const float*)d_in[12];
    const float* up3_w = (const float*)d_in[13];
    const float* up3_b = (const float*)d_in[14];
    const float* bn_in_s = (const float*)d_in[15];
    const float* bn_in_o = (const float*)d_in[16];
    const float* bn_d1_s = (const float*)d_in[17];
    const float* bn_d1_o = (const float*)d_in[18];
    const float* bn_d2_s = (const float*)d_in[19];
    const float* bn_d2_o = (const float*)d_in[20];
    const float* bn_u1_s = (const float*)d_in[21];
    const float* bn_u1_o = (const float*)d_in[22];
    const float* bn_u2_s = (const float*)d_in[23];
    const float* bn_u2_o = (const float*)d_in[24];
    const float* bn_u3_s = (const float*)d_in[25];
    const float* bn_u3_o = (const float*)d_in[26];
    const float* gru_wi = (const float*)d_in[27];
    const float* gru_wh = (const float*)d_in[28];
    const float* gru_b = (const float*)d_in[29];
    const float* o1_w = (const float*)d_in[30];
    const float* o1_b = (const float*)d_in[31];
    const float* o2_w = (const float*)d_in[32];
    const float* o2_b = (const float*)d_in[33];

    float* ws = (float*)d_ws;
    float* out = (float*)d_out;

    unsigned long long* fRH = (unsigned long long*)(ws + OFF_FRH);
    unsigned long long* fH  = (unsigned long long*)(ws + OFF_FH);
    unsigned long long* sRH = (unsigned long long*)(ws + OFF_SRH);
    unsigned long long* sH  = (unsigned long long*)(ws + OFF_SH);
    unsigned* bar = (unsigned*)(ws + OFF_BAR);
    float* mean = ws + OFF_MEAN;
    float* scale = ws + OFF_SCALE;
    float* offs = ws + OFF_OFFS;
    float* u0 = ws + OFF_U0;
    float* u0n = ws + OFF_U0N;
    float* r1 = ws + OFF_R1;
    float* u1 = ws + OFF_U1;
    float* r2 = ws + OFF_R2;
    float* u2 = ws + OFF_U2;
    float* y1 = ws + OFF_Y1;
    float* v1 = ws + OFF_V1;
    float* y2 = ws + OFF_Y2;
    float* v2 = ws + OFF_V2;
    float* y3 = ws + OFF_Y3;
    float* cond0 = ws + OFF_COND0;
    float* ewi = ws + OFF_EWI;
    float* cgx = ws + OFF_CGX;
    float* hseq = ws + OFF_HSEQ;

    init_kernel<<<64, 256, 0, stream>>>(fRH, bar);

    // conv_in (K3, rate1) + BN + relu
    conv1d_kernel<<<8 * 38, 512, 240 * 4, stream>>>(mel, conv_in_w, conv_in_b, u0, 40, 38, 80, 3, 1);
    bnstats_kernel<<<512, 64, 0, stream>>>(u0, bn_in_s, bn_in_o, mean, scale, offs, 304, 512);
    bnapply_kernel<<<155648 / 256, 256, 0, stream>>>(u0, u0n, mean, scale, offs, 155648);
    // dilated resblock 1
    conv1d_kernel<<<8 * 36, 512, 1024 * 4, stream>>>(u0n, conv_d1_w, conv_d1_b, r1, 38, 36, 512, 2, 2);
    bnstats_kernel<<<512, 64, 0, stream>>>(r1, bn_d1_s, bn_d1_o, mean, scale, offs, 288, 512);
    bnapply_add_kernel<<<147456 / 256, 256, 0, stream>>>(r1, u0n, u1, mean, scale, offs, 36, 38, 1);
    // dilated resblock 2
    conv1d_kernel<<<8 * 32, 512, 1024 * 4, stream>>>(u1, conv_d2_w, conv_d2_b, r2, 36, 32, 512, 2, 4);
    bnstats_kernel<<<512, 64, 0, stream>>>(r2, bn_d2_s, bn_d2_o, mean, scale, offs, 256, 512);
    bnapply_add_kernel<<<131072 / 256, 256, 0, stream>>>(r2, u1, u2, mean, scale, offs, 32, 36, 2);
    // upsample x2, x2, x4
    tconv1d_kernel<<<8 * 64, 512, 2048, stream>>>(u2, up1_w, up1_b, y1, 32, 2, 512);
    bnstats_kernel<<<512, 64, 0, stream>>>(y1, bn_u1_s, bn_u1_o, mean, scale, offs, 512, 512);
    bnapply_kernel<<<262144 / 256, 256, 0, stream>>>(y1, v1, mean, scale, offs, 262144);
    tconv1d_kernel<<<8 * 128, 512, 2048, stream>>>(v1, up2_w, up2_b, y2, 64, 2, 512);
    bnstats_kernel<<<512, 64, 0, stream>>>(y2, bn_u2_s, bn_u2_o, mean, scale, offs, 1024, 512);
    bnapply_kernel<<<524288 / 256, 256, 0, stream>>>(y2, v2, mean, scale, offs, 524288);
    tconv1d_kernel<<<8 * 512, 512, 2048, stream>>>(v2, up3_w, up3_b, y3, 128, 4, 512);
    bnstats_kernel<<<512, 64, 0, stream>>>(y3, bn_u3_s, bn_u3_o, mean, scale, offs, 4096, 512);
    bnapply_kernel<<<2097152 / 256, 256, 0, stream>>>(y3, cond0, mean, scale, offs, 2097152);

    // collapsed gx: ewi = embed@wi (256x1536), cgx = cond0@wi (4096x1536)
    rowgemm_kernel<<<16, 256, 0, stream>>>(embed_w, gru_wi, ewi, 256);
    rowgemm_kernel<<<256, 256, 0, stream>>>(cond0, gru_wi, cgx, 4096);

    // persistent GRU: 256 wgs x 512 threads, ~104KB dynamic LDS (1 wg/CU)
    hipFuncSetAttribute(reinterpret_cast<const void*>(gru_kernel),
                        hipFuncAttributeMaxDynamicSharedMemorySize,
                        (int)(GRU_SMEM_FLOATS * sizeof(float)));
    gru_kernel<<<256, 512, GRU_SMEM_FLOATS * sizeof(float), stream>>>(
        gru_wh, gru_b, x, ewi, cgx, fRH, fH, sRH, sH, bar, hseq);

    // fused output head + log_softmax
    head_kernel<<<4096, 256, 0, stream>>>(hseq, o1_w, o1_b, o2_w, o2_b, out);
}